// Round 15
// baseline (114.588 us; speedup 1.0000x reference)
//
#include <hip/hip_runtime.h>
#include <hip/hip_bf16.h>

#define N_TOK  32768
#define F_IN   80
#define D_DIM  512
#define K_CENT 2048
#define F_OUT  80
#define TM     16
#define M2     0.5f      // margin in acc units (dist = -2*score)
#define QSLOTS 24
#define QREC   200       // 8B header {cnt,max} + 24 * 8B records
#define TREC   800       // 4 quarters per token (100 x 8B flat slots)
#define JTOT   160       // Bcat width: 80 dec | 80 G

typedef __attribute__((ext_vector_type(8)))  short bf16x8;
typedef __attribute__((ext_vector_type(4)))  float fx4;
typedef __attribute__((ext_vector_type(16))) float fx16;

#define AS3 __attribute__((address_space(3)))
#define AS1 __attribute__((address_space(1)))

__device__ inline unsigned short f2bf(float f) {
    unsigned u = __float_as_uint(f);
    return (unsigned short)((u + 0x7FFFu + ((u >> 16) & 1u)) >> 16);
}

__device__ inline void gll16(const unsigned short* g, unsigned short* l) {
    __builtin_amdgcn_global_load_lds((const AS1 unsigned*)g, (AS3 unsigned*)l, 16, 0, 0);
}

__device__ inline unsigned fkey(float f) {
    unsigned b = __float_as_uint(f);
    return b ^ ((b >> 31) ? 0xFFFFFFFFu : 0x80000000u);
}
__device__ inline float keyf(unsigned k) {
    unsigned b = k ^ ((k & 0x80000000u) ? 0x80000000u : 0xFFFFFFFFu);
    return __uint_as_float(b);
}

// K=16 fragment-linear tile [128 rows][16 k] = 2048 elems (32x32x16 operand):
// sub = row>>5; lane L = (row&31) + 32*(k>>3); elem at sub*512 + L*8 + (k&7)
__device__ inline size_t frag16_addr(int row, int k) {
    return (size_t)(row >> 5) * 512 + (size_t)((row & 31) + ((k >> 3) << 5)) * 8 + (k & 7);
}

// ============================ kernel 1: xbt + Bcat + cnorm/cadjs ============================
// blocks    0..1279: x -> xbt (frag16 tiles [256 mt][5 kt][2048], K=80 exact, no pad)
// blocks 1280..1599: Bcat[d][j] = (j<80) ? Wdec[d][j] : Wenc[j-80][d]
// blocks 1600..2111: per 4 centroids (wave each): cnorm[k], cadjs[k] = 0.5*(||c||^2 - 2 b.c)
__global__ __launch_bounds__(256) void k_prep1(
    const float* __restrict__ x, const float* __restrict__ Wenc,
    const float* __restrict__ Wdec, const float* __restrict__ cent,
    const float* __restrict__ benc,
    unsigned short* __restrict__ xbt, float* __restrict__ Bcat,
    float* __restrict__ cnorm, float* __restrict__ cadjs) {
    const int bid = blockIdx.x, tid = threadIdx.x;
    if (bid < 1280) {
        // ---- xbt ----
        int o = bid * 256 + tid;    // 327680 octets
        int m = o / 10;
        int ko = (o - m * 10) * 8;  // 0..72, always < 80
        const float* src = x + (size_t)m * F_IN + ko;
        float4 v0 = *(const float4*)src;
        float4 v1 = *(const float4*)(src + 4);
        int mt = m >> 7, kt = ko >> 4, row = m & 127, kl = ko & 15;
        uint4 p;
        p.x = (unsigned)f2bf(v0.x) | ((unsigned)f2bf(v0.y) << 16);
        p.y = (unsigned)f2bf(v0.z) | ((unsigned)f2bf(v0.w) << 16);
        p.z = (unsigned)f2bf(v1.x) | ((unsigned)f2bf(v1.y) << 16);
        p.w = (unsigned)f2bf(v1.z) | ((unsigned)f2bf(v1.w) << 16);
        *(uint4*)&xbt[(size_t)(mt * 5 + kt) * 2048 + frag16_addr(row, kl)] = p;
    } else if (bid < 1600) {
        // ---- Bcat ----
        int e = (bid - 1280) * 256 + tid;      // 81920 elems
        int d = e / JTOT, j = e - d * JTOT;
        float v = (j < F_OUT) ? Wdec[(size_t)d * F_OUT + j]
                              : Wenc[(size_t)(j - F_OUT) * D_DIM + d];
        Bcat[e] = v;
    } else {
        // ---- cnorm + cadjs ----
        int wave = tid >> 6, lane = tid & 63;
        int k = (bid - 1600) * 4 + wave;
        const float* row = cent + (size_t)k * D_DIM;
        float s = 0.f, t = 0.f;
#pragma unroll
        for (int j = 0; j < 8; ++j) {
            float c = row[lane + 64 * j];
            float b = benc[lane + 64 * j];
            s += c * c; t += b * c;
        }
#pragma unroll
        for (int off = 32; off; off >>= 1) { s += __shfl_down(s, off); t += __shfl_down(t, off); }
        if (lane == 0) {
            cnorm[k] = s;
            cadjs[k] = 0.5f * (s - 2.0f * t);
        }
    }
}

// ============================ kernel 2: fused dec + G GEMM (f32 VALU, d-split) ============================
// 512 blocks x 384 thr: thread = (j = tid%192, dh = tid/192); block = 4 centroids.
__global__ __launch_bounds__(384) void k_cgemm2(
    const float* __restrict__ cent, const float* __restrict__ Bcat,
    const float* __restrict__ bdec, unsigned short* __restrict__ Gbt,
    float* __restrict__ dec) {
    __shared__ float pacc[192][4];   // dh=1 partials, 3 KB
    const int tid = threadIdx.x;
    const int j = tid % 192;
    const int dh = tid / 192;
    const int k0 = blockIdx.x * 4;
    float a0 = 0.f, a1 = 0.f, a2 = 0.f, a3 = 0.f;
    if (j < JTOT) {
        const float* c0 = cent + (size_t)k0 * D_DIM + dh * 256;
        const float* bp = Bcat + (size_t)dh * 256 * JTOT + j;
#pragma unroll 4
        for (int d = 0; d < 256; ++d) {
            float b  = bp[d * JTOT];
            a0 += c0[d] * b;
            a1 += c0[D_DIM + d] * b;
            a2 += c0[2 * D_DIM + d] * b;
            a3 += c0[3 * D_DIM + d] * b;
        }
        if (dh == 1) { pacc[j][0] = a0; pacc[j][1] = a1; pacc[j][2] = a2; pacc[j][3] = a3; }
    }
    __syncthreads();
    if (dh == 0 && j < JTOT) {
        a0 += pacc[j][0]; a1 += pacc[j][1]; a2 += pacc[j][2]; a3 += pacc[j][3];
        float a[4] = { a0, a1, a2, a3 };
        if (j < F_OUT) {
            float bd = bdec[j];
#pragma unroll
            for (int c = 0; c < 4; ++c)
                dec[(size_t)(k0 + c) * F_OUT + j] = a[c] + bd;
        } else {
            int f = j - F_OUT;   // 0..79
#pragma unroll
            for (int c = 0; c < 4; ++c) {
                int k = k0 + c;
                size_t tile = (size_t)((k >> 7) * 5 + (f >> 4));
                Gbt[tile * 2048 + frag16_addr(k & 127, f & 15)] = f2bf(a[c]);
            }
        }
    }
}

// ============================ distance + per-token argmax + candidates ============================
// 1024 blocks = (256 mt) x (4 nq); 512 thr = 4 token-groups x 2 centroid-halves.
// 32x32x16 MFMA, swapped operands (token = lane&31). score = x.G - 0.5*cadj (exact f32 subtract).
__global__ __launch_bounds__(512) void k_dist5(
    const unsigned short* __restrict__ xbt, const unsigned short* __restrict__ Gbt,
    const float* __restrict__ cadjs, char* __restrict__ lists) {
    __shared__ unsigned short Bs[2][10240];   // 40 KB dbuf (5 kt-tiles of K=16)
    __shared__ float cadjq[512];
    __shared__ int cnt[128];
    __shared__ unsigned mxk[128];

    const int tid = threadIdx.x;
    const int bid = blockIdx.x;
    const int mt = bid >> 2, nq = bid & 3;
    const int lane = tid & 63;
    const int wave = tid >> 6;
    const int tg = wave >> 1;       // token group: tokens tg*32..+31
    const int ch = wave & 1;        // centroid half: rows {ch*2, ch*2+1}*32 of tile
    const int col = lane & 31;
    const int hi = lane >> 5;

    if (tid < 128) { cnt[tid] = 0; mxk[tid] = 0u; }
    cadjq[tid] = cadjs[nq * 512 + tid];   // 512 threads cover all

    // token fragments (B operand) from xbt: coalesced 16B/lane
    bf16x8 bfr[5];
    const unsigned short* Ab = xbt + (size_t)mt * 5 * 2048;
#pragma unroll
    for (int kc = 0; kc < 5; ++kc)
        bfr[kc] = *(const bf16x8*)&Ab[kc * 2048 + tg * 512 + lane * 8];

    const int woff = (tid & ~63) * 8;
    const unsigned short* Gq = Gbt + (size_t)nq * 4 * 10240;
    // stage G-tile 0 (20 KB)
    {
        const unsigned short* src = Gq;
        unsigned short* dst = &Bs[0][0];
#pragma unroll
        for (int q = 0; q < 2; ++q)
            gll16(src + q * 4096 + tid * 8, dst + q * 4096 + woff);
        if (tid < 256)
            gll16(src + 8192 + tid * 8, dst + 8192 + woff);
    }

    float rmax = -3.4e38f;
    int cur = 0;
    for (int t4 = 0; t4 < 4; ++t4) {
        __syncthreads();   // staging of buf[cur] + cadjq complete
        if (t4 + 1 < 4) {
            const unsigned short* src = Gq + (size_t)(t4 + 1) * 10240;
            unsigned short* dst = &Bs[cur ^ 1][0];
#pragma unroll
            for (int q = 0; q < 2; ++q)
                gll16(src + q * 4096 + tid * 8, dst + q * 4096 + woff);
            if (tid < 256)
                gll16(src + 8192 + tid * 8, dst + 8192 + woff);
        }
        const unsigned short* B = &Bs[cur][0];
        fx16 acc[2];
#pragma unroll
        for (int u = 0; u < 2; ++u)
#pragma unroll
            for (int r = 0; r < 16; ++r) acc[u][r] = 0.f;
#pragma unroll
        for (int kc = 0; kc < 5; ++kc) {
#pragma unroll
            for (int u = 0; u < 2; ++u) {
                bf16x8 a = *(const bf16x8*)&B[kc * 2048 + (ch * 2 + u) * 512 + lane * 8];
                acc[u] = __builtin_amdgcn_mfma_f32_32x32x16_bf16(a, bfr[kc], acc[u], 0, 0, 0);
            }
        }
        // score = acc - 0.5*cadj (broadcast LDS reads), running max + pushes
        float sc[2][16];
#pragma unroll
        for (int u = 0; u < 2; ++u)
#pragma unroll
            for (int r = 0; r < 16; ++r) {
                int rowLoc = (ch * 2 + u) * 32 + (r & 3) + 8 * (r >> 2) + 4 * hi;
                sc[u][r] = acc[u][r] - cadjq[t4 * 128 + rowLoc];
            }
        float m = sc[0][0];
#pragma unroll
        for (int r = 1; r < 16; ++r) m = fmaxf(m, sc[0][r]);
#pragma unroll
        for (int r = 0; r < 16; ++r) m = fmaxf(m, sc[1][r]);
        m = fmaxf(m, __shfl_xor(m, 32));
        rmax = fmaxf(rmax, m);
        const float th = rmax - M2;
        const int tk = tg * 32 + col;
        char* qrec = lists + (size_t)(mt * 128 + tk) * TREC + nq * QREC;
#pragma unroll
        for (int u = 0; u < 2; ++u)
#pragma unroll
            for (int r = 0; r < 16; ++r) {
                float v = sc[u][r];
                if (v >= th) {
                    int slot = atomicAdd(&cnt[tk], 1);
                    if (slot < QSLOTS) {
                        uint2 e;
                        e.x = __float_as_uint(v);
                        e.y = (unsigned)(nq * 512 + t4 * 128 + (ch * 2 + u) * 32
                                         + (r & 3) + 8 * (r >> 2) + 4 * hi);
                        *(uint2*)(qrec + 8 + slot * 8) = e;
                    }
                }
            }
        cur ^= 1;
    }
    if (lane < 32) atomicMax(&mxk[tg * 32 + lane], fkey(rmax));
    __syncthreads();
    if (tid < 128) {
        uint2 h;
        h.x = (unsigned)cnt[tid];
        h.y = __float_as_uint(keyf(mxk[tid]));
        *(uint2*)(lists + (size_t)(mt * 128 + tid) * TREC + nq * QREC) = h;
    }
}

// ============================ merge (1 token/wave) + exact-refine + decode gather ============================
__global__ __launch_bounds__(256) void k_merge4(
    const char* __restrict__ lists, const float* __restrict__ cnorm,
    const float* __restrict__ cent, const float* __restrict__ x,
    const float* __restrict__ Wenc, const float* __restrict__ benc,
    const float* __restrict__ dec, float* __restrict__ out) {
    const int lane = threadIdx.x & 63;
    const int token = blockIdx.x * 4 + (threadIdx.x >> 6);   // 8192 blocks x 4 waves
    const char* base = lists + (size_t)token * TREC;
    uint4 w4 = make_uint4(0u, 0u, 0u, 0u);
    if (lane < 50) w4 = *(const uint4*)(base + lane * 16);
    const int   c0 = __shfl((int)w4.x, 0),  c1 = __shfl((int)w4.z, 12);
    const int   c2 = __shfl((int)w4.x, 25), c3 = __shfl((int)w4.z, 37);
    const float m0 = __uint_as_float((unsigned)__shfl((int)w4.y, 0));
    const float m1 = __uint_as_float((unsigned)__shfl((int)w4.w, 12));
    const float m2 = __uint_as_float((unsigned)__shfl((int)w4.y, 25));
    const float m3 = __uint_as_float((unsigned)__shfl((int)w4.w, 37));
    const float gm = fmaxf(fmaxf(m0, m1), fmaxf(m2, m3));
    const float th = gm - M2;
    const bool ovf = (c0 > QSLOTS) || (c1 > QSLOTS) || (c2 > QSLOTS) || (c3 > QSLOTS);
    const int q0c = c0 < QSLOTS ? c0 : QSLOTS, q1c = c1 < QSLOTS ? c1 : QSLOTS;
    const int q2c = c2 < QSLOTS ? c2 : QSLOTS, q3c = c3 < QSLOTS ? c3 : QSLOTS;
    bool cd[2];
#pragma unroll
    for (int rr = 0; rr < 2; ++rr) {
        int t = lane * 2 + rr;
        int q = t / 25, s = t - q * 25;
        int cq = (q == 0) ? q0c : (q == 1) ? q1c : (q == 2) ? q2c : q3c;
        float v = __uint_as_float(rr ? w4.z : w4.x);
        cd[rr] = (lane < 50) && (s >= 1) && (s - 1 < cq) && (v >= th);
    }
    unsigned long long b0 = __ballot(cd[0]);
    unsigned long long b1 = __ballot(cd[1]);
    int ns = __popcll(b0) + __popcll(b1);
    int ans;
    if (!ovf && ns == 1) {
        if (b0) ans = __shfl((int)w4.y, __ffsll(b0) - 1);
        else    ans = __shfl((int)w4.w, __ffsll(b1) - 1);
    } else {
        float z8[8];
#pragma unroll
        for (int j = 0; j < 8; ++j) z8[j] = benc[lane * 8 + j];
        const float* xr = x + (size_t)token * F_IN;
        const float* wp = Wenc + lane * 8;
        for (int f = 0; f < F_IN; ++f) {
            float xf = xr[f];
            fx4 w0 = *(const fx4*)(wp + (size_t)f * D_DIM);
            fx4 w1 = *(const fx4*)(wp + (size_t)f * D_DIM + 4);
            z8[0] += xf * w0.x; z8[1] += xf * w0.y; z8[2] += xf * w0.z; z8[3] += xf * w0.w;
            z8[4] += xf * w1.x; z8[5] += xf * w1.y; z8[6] += xf * w1.z; z8[7] += xf * w1.w;
        }
        float bd = 1e30f; int bn = 0x7FFFFFFF;
        auto exact1 = [&](int ci) {
            const float* cr = cent + (size_t)ci * D_DIM + lane * 8;
            fx4 cc0 = *(const fx4*)cr, cc1 = *(const fx4*)(cr + 4);
            float dp = z8[0] * cc0.x + z8[1] * cc0.y + z8[2] * cc0.z + z8[3] * cc0.w
                     + z8[4] * cc1.x + z8[5] * cc1.y + z8[6] * cc1.z + z8[7] * cc1.w;
#pragma unroll
            for (int off = 1; off < 64; off <<= 1) dp += __shfl_xor(dp, off);
            float de = cnorm[ci] - 2.0f * dp;
            if (de < bd || (de == bd && ci < bn)) { bd = de; bn = ci; }
        };
        unsigned long long m = b0;
        while (m) { int src = __ffsll(m) - 1; m &= m - 1; exact1(__shfl((int)w4.y, src)); }
        m = b1;
        while (m) { int src = __ffsll(m) - 1; m &= m - 1; exact1(__shfl((int)w4.w, src)); }
        if (ovf) {
#pragma unroll
            for (int q = 0; q < 4; ++q) {
                int cf = (q == 0) ? c0 : (q == 1) ? c1 : (q == 2) ? c2 : c3;
                if (cf > QSLOTS)
                    for (int n0 = 0; n0 < 512; ++n0) exact1(q * 512 + n0);
            }
        }
        ans = bn;
    }
    const float* dr = dec + (size_t)ans * F_OUT;
    float* orow = out + (size_t)token * F_OUT;
    orow[lane] = dr[lane];
    if (lane < F_OUT - 64) orow[64 + lane] = dr[64 + lane];
}

// ============================ fallback path (round-1, known-good) ============================
__global__ void k_transpose(const float* __restrict__ cent, float* __restrict__ centT) {
    __shared__ float tile[64][65];
    int kb = blockIdx.x * 64, db = blockIdx.y * 64;
    int lx = threadIdx.x & 63, ly = threadIdx.x >> 6;
#pragma unroll
    for (int i = 0; i < 16; ++i) {
        int row = ly + i * 4;
        tile[row][lx] = cent[(size_t)(kb + row) * D_DIM + db + lx];
    }
    __syncthreads();
#pragma unroll
    for (int i = 0; i < 16; ++i) {
        int row = ly + i * 4;
        centT[(size_t)(db + row) * K_CENT + kb + lx] = tile[lx][row];
    }
}

__global__ void k_cnorm(const float* __restrict__ cent, float* __restrict__ cnorm) {
    int wave = threadIdx.x >> 6, lane = threadIdx.x & 63;
    int k = blockIdx.x * 4 + wave;
    const float* row = cent + (size_t)k * D_DIM;
    float s = 0.f;
#pragma unroll
    for (int j = 0; j < 8; ++j) { float v = row[lane + 64 * j]; s += v * v; }
#pragma unroll
    for (int off = 32; off; off >>= 1) s += __shfl_down(s, off);
    if (lane == 0) cnorm[k] = s;
}

__global__ void k_dec(const float* __restrict__ cent, const float* __restrict__ Wdec,
                      const float* __restrict__ bdec, float* __restrict__ dec) {
    __shared__ float cs[D_DIM];
    int k = blockIdx.x;
    for (int d = threadIdx.x; d < D_DIM; d += blockDim.x) cs[d] = cent[(size_t)k * D_DIM + d];
    __syncthreads();
    int f = threadIdx.x;
    if (f < F_OUT) {
        float a0 = 0.f, a1 = 0.f, a2 = 0.f, a3 = 0.f;
#pragma unroll 4
        for (int d = 0; d < D_DIM; d += 4) {
            a0 += cs[d + 0] * Wdec[(d + 0) * F_OUT + f];
            a1 += cs[d + 1] * Wdec[(d + 1) * F_OUT + f];
            a2 += cs[d + 2] * Wdec[(d + 2) * F_OUT + f];
            a3 += cs[d + 3] * Wdec[(d + 3) * F_OUT + f];
        }
        dec[(size_t)k * F_OUT + f] = a0 + a1 + a2 + a3 + bdec[f];
    }
}

__global__ void k_out(const float* __restrict__ dec, const int* __restrict__ idx,
                      float* __restrict__ out) {
    int e0 = blockIdx.x * 2560;
#pragma unroll
    for (int r = 0; r < 10; ++r) {
        int e = e0 + threadIdx.x + r * 256;
        int n = e / F_OUT, f = e - n * F_OUT;
        out[e] = dec[(size_t)idx[n] * F_OUT + f];
    }
}

__global__ __launch_bounds__(256) void k_main(
    const float* __restrict__ x, const float* __restrict__ Wenc,
    const float* __restrict__ benc, const float* __restrict__ centT,
    const float* __restrict__ cnorm, int* __restrict__ idxOut) {
    __shared__ float xs[TM * F_IN];
    __shared__ float zs[TM][D_DIM];
    float* pv = &zs[0][0];
    int*   pi = (int*)(&zs[0][0] + 256 * TM);
    const int tid = threadIdx.x;
    const int tok0 = blockIdx.x * TM;
    for (int e = tid; e < TM * F_IN; e += 256) xs[e] = x[(size_t)tok0 * F_IN + e];
    __syncthreads();
    {
        float acc0[TM], acc1[TM];
#pragma unroll
        for (int t = 0; t < TM; ++t) { acc0[t] = 0.f; acc1[t] = 0.f; }
        const float2 b2 = ((const float2*)benc)[tid];
#pragma unroll 4
        for (int f4 = 0; f4 < F_IN; f4 += 4) {
            float2 w0 = ((const float2*)(Wenc + (size_t)(f4 + 0) * D_DIM))[tid];
            float2 w1 = ((const float2*)(Wenc + (size_t)(f4 + 1) * D_DIM))[tid];
            float2 w2 = ((const float2*)(Wenc + (size_t)(f4 + 2) * D_DIM))[tid];
            float2 w3 = ((const float2*)(Wenc + (size_t)(f4 + 3) * D_DIM))[tid];
#pragma unroll
            for (int t = 0; t < TM; ++t) {
                float4 xv = *(const float4*)&xs[t * F_IN + f4];
                acc0[t] += xv.x * w0.x + xv.y * w1.x + xv.z * w2.x + xv.w * w3.x;
                acc1[t] += xv.x * w0.y + xv.y * w1.y + xv.z * w2.y + xv.w * w3.y;
            }
        }
#pragma unroll
        for (int t = 0; t < TM; ++t)
            *(float2*)&zs[t][2 * tid] = make_float2(acc0[t] + b2.x, acc1[t] + b2.y);
    }
    __syncthreads();
    float minv[TM]; int mini[TM];
#pragma unroll
    for (int t = 0; t < TM; ++t) { minv[t] = 3.4e38f; mini[t] = 0; }
    for (int iter = 0; iter < 2; ++iter) {
        float acc[4][TM];
#pragma unroll
        for (int j = 0; j < 4; ++j)
#pragma unroll
            for (int t = 0; t < TM; ++t) acc[j][t] = 0.f;
        const int cbase = iter * 1024 + tid;
        for (int d4 = 0; d4 < D_DIM; d4 += 4) {
            float cv[4][4];
#pragma unroll
            for (int dd = 0; dd < 4; ++dd) {
                const float* cp = centT + (size_t)(d4 + dd) * K_CENT + cbase;
                cv[dd][0] = cp[0]; cv[dd][1] = cp[256]; cv[dd][2] = cp[512]; cv[dd][3] = cp[768];
            }
#pragma unroll
            for (int t = 0; t < TM; ++t) {
                float4 zv = *(const float4*)&zs[t][d4];
#pragma unroll
                for (int j = 0; j < 4; ++j)
                    acc[j][t] += zv.x * cv[0][j] + zv.y * cv[1][j] + zv.z * cv[2][j] + zv.w * cv[3][j];
            }
        }
#pragma unroll
        for (int j = 0; j < 4; ++j) {
            int c = cbase + j * 256;
            float cn = cnorm[c];
#pragma unroll
            for (int t = 0; t < TM; ++t) {
                float dist = cn - 2.f * acc[j][t];
                if (dist < minv[t]) { minv[t] = dist; mini[t] = c; }
            }
        }
    }
    __syncthreads();
#pragma unroll
    for (int t = 0; t < TM; ++t) { pv[tid * TM + t] = minv[t]; pi[tid * TM + t] = mini[t]; }
    __syncthreads();
    {
        int t = tid & 15, g = tid >> 4;
        float bv = 3.4e38f; int bi = 0x7fffffff;
        for (int j = 0; j < 16; ++j) {
            int r2 = g + 16 * j;
            float vv = pv[r2 * TM + t]; int i2 = pi[r2 * TM + t];
            if (vv < bv || (vv == bv && i2 < bi)) { bv = vv; bi = i2; }
        }
        pv[g * TM + t] = bv; pi[g * TM + t] = bi;
    }
    __syncthreads();
    if (tid < TM) {
        int t = tid;
        float bv = 3.4e38f; int bi = 0x7fffffff;
        for (int g = 0; g < 16; ++g) {
            float vv = pv[g * TM + t]; int i2 = pi[g * TM + t];
            if (vv < bv || (vv == bv && i2 < bi)) { bv = vv; bi = i2; }
        }
        idxOut[tok0 + t] = bi;
    }
}

// ============================ launch ============================
extern "C" void kernel_launch(void* const* d_in, const int* in_sizes, int n_in,
                              void* d_out, int out_size, void* d_ws, size_t ws_size,
                              hipStream_t stream) {
    const float* x    = (const float*)d_in[0];
    const float* Wenc = (const float*)d_in[1];
    const float* benc = (const float*)d_in[2];
    const float* cent = (const float*)d_in[3];
    const float* Wdec = (const float*)d_in[4];
    const float* bdec = (const float*)d_in[5];
    float* out = (float*)d_out;

    const size_t L_B  = (size_t)N_TOK * TREC;            // 26214400 candidate lists
    const size_t XB_B = (size_t)N_TOK * F_IN * 2;        //  5242880 xbt (K=80)
    const size_t GB_B = (size_t)K_CENT * F_IN * 2;       //   327680 Gbt (K=80)
    const size_t N_B  = (size_t)K_CENT * 4;              //     8192 cnorm
    const size_t A_B  = (size_t)K_CENT * 4;              //     8192 cadjs
    const size_t D_B  = (size_t)K_CENT * F_OUT * 4;      //   655360 dec
    const size_t BC_B = (size_t)D_DIM * JTOT * 4;        //   327680 Bcat
    const size_t NEED = L_B + XB_B + GB_B + N_B + A_B + D_B + BC_B;

    if (ws_size >= NEED) {
        char* w = (char*)d_ws;
        char*           lists = w;                            w += L_B;
        unsigned short* xbt   = (unsigned short*)w;           w += XB_B;
        unsigned short* Gbt   = (unsigned short*)w;           w += GB_B;
        float*          cnorm = (float*)w;                    w += N_B;
        float*          cadjs = (float*)w;                    w += A_B;
        float*          dec   = (float*)w;                    w += D_B;
        float*          Bcat  = (float*)w;

        k_prep1<<<2112, 256, 0, stream>>>(x, Wenc, Wdec, cent, benc,
                                          xbt, Bcat, cnorm, cadjs);
        k_cgemm2<<<K_CENT / 4, 384, 0, stream>>>(cent, Bcat, bdec, Gbt, dec);
        k_dist5<<<1024, 512, 0, stream>>>(xbt, Gbt, cadjs, lists);
        k_merge4<<<N_TOK / 4, 256, 0, stream>>>(lists, cnorm, cent, x, Wenc, benc, dec, out);
    } else {
        float* centT = (float*)d_ws;
        float* cnorm = centT + (size_t)D_DIM * K_CENT;
        float* dec   = cnorm + K_CENT;
        int*   idx   = (int*)(dec + (size_t)K_CENT * F_OUT);
        k_transpose<<<dim3(K_CENT / 64, D_DIM / 64), 256, 0, stream>>>(cent, centT);
        k_cnorm<<<K_CENT / 4, 256, 0, stream>>>(cent, cnorm);
        k_dec<<<K_CENT, 128, 0, stream>>>(cent, Wdec, bdec, dec);
        k_main<<<N_TOK / TM, 256, 0, stream>>>(x, Wenc, benc, centT, cnorm, idx);
        k_out<<<N_TOK * F_OUT / 2560, 256, 0, stream>>>(dec, idx, out);
    }
}

// Round 16
// 99.834 us; speedup vs baseline: 1.1478x; 1.1478x over previous
//
#include <hip/hip_runtime.h>
#include <hip/hip_bf16.h>

#define N_TOK  32768
#define F_IN   80
#define D_DIM  512
#define K_CENT 2048
#define F_OUT  80
#define TM     16
#define KP     96
#define M2     0.5f      // margin in acc units (dist = -2*acc)
#define QSLOTS 24
#define QREC   200       // 8B header {cnt,max} + 24 * 8B records
#define TREC   800       // 4 quarters per token (100 x 8B flat slots)
#define JTOT   160       // Bcat width: 80 dec | 80 G

typedef __attribute__((ext_vector_type(8)))  short bf16x8;
typedef __attribute__((ext_vector_type(4)))  float fx4;
typedef __attribute__((ext_vector_type(16))) float fx16;

#define AS3 __attribute__((address_space(3)))
#define AS1 __attribute__((address_space(1)))

__device__ inline unsigned short f2bf(float f) {
    unsigned u = __float_as_uint(f);
    return (unsigned short)((u + 0x7FFFu + ((u >> 16) & 1u)) >> 16);
}
__device__ inline float bf2f(unsigned short h) {
    return __uint_as_float((unsigned)h << 16);
}

__device__ inline void gll16(const unsigned short* g, unsigned short* l) {
    __builtin_amdgcn_global_load_lds((const AS1 unsigned*)g, (AS3 unsigned*)l, 16, 0, 0);
}

__device__ inline unsigned fkey(float f) {
    unsigned b = __float_as_uint(f);
    return b ^ ((b >> 31) ? 0xFFFFFFFFu : 0x80000000u);
}
__device__ inline float keyf(unsigned k) {
    unsigned b = k ^ ((k & 0x80000000u) ? 0x80000000u : 0xFFFFFFFFu);
    return __uint_as_float(b);
}

// 32x32x16 fragment-linear tile [128 rows][32 k] (dist operands)
__device__ inline size_t frag32_addr(int row, int k) {
    int sub = (row >> 5) * 2 + ((k >> 4) & 1);
    int L = (row & 31) + ((k >> 3) & 1) * 32;
    return (size_t)sub * 512 + L * 8 + (k & 7);
}

// ============================ kernel 1: xbt + Bcat + cnorm/cadj-fold ============================
__global__ __launch_bounds__(256) void k_prep1(
    const float* __restrict__ x, const float* __restrict__ Wenc,
    const float* __restrict__ Wdec, const float* __restrict__ cent,
    const float* __restrict__ benc,
    unsigned short* __restrict__ xbt, float* __restrict__ Bcat,
    float* __restrict__ cnorm, unsigned short* __restrict__ Gbt) {
    const int bid = blockIdx.x, tid = threadIdx.x;
    if (bid < 1536) {
        // ---- xbt (frag32, dims 80,81 = 1.0 for cadj fold, 82..95 = 0) ----
        int o = bid * 256 + tid;    // 393216 octets
        int m = o / 12;
        int ko = (o - m * 12) * 8;
        unsigned short u[8];
        if (ko < F_IN) {
            const float* src = x + (size_t)m * F_IN + ko;
            float4 v0 = *(const float4*)src;
            float4 v1 = *(const float4*)(src + 4);
            u[0]=f2bf(v0.x); u[1]=f2bf(v0.y); u[2]=f2bf(v0.z); u[3]=f2bf(v0.w);
            u[4]=f2bf(v1.x); u[5]=f2bf(v1.y); u[6]=f2bf(v1.z); u[7]=f2bf(v1.w);
        } else if (ko == 80) {
            u[0] = 0x3F80; u[1] = 0x3F80;
#pragma unroll
            for (int j = 2; j < 8; ++j) u[j] = 0;
        } else {
#pragma unroll
            for (int j = 0; j < 8; ++j) u[j] = 0;
        }
        int mt = m >> 7, kt = ko >> 5, row = m & 127, kl = ko & 31;
        uint4 p;
        p.x = (unsigned)u[0] | ((unsigned)u[1] << 16);
        p.y = (unsigned)u[2] | ((unsigned)u[3] << 16);
        p.z = (unsigned)u[4] | ((unsigned)u[5] << 16);
        p.w = (unsigned)u[6] | ((unsigned)u[7] << 16);
        *(uint4*)&xbt[(size_t)(mt * 3 + kt) * 4096 + frag32_addr(row, kl)] = p;
    } else if (bid < 1856) {
        // ---- Bcat ----
        int e = (bid - 1536) * 256 + tid;      // 81920 elems
        int d = e / JTOT, j = e - d * JTOT;
        float v = (j < F_OUT) ? Wdec[(size_t)d * F_OUT + j]
                              : Wenc[(size_t)(j - F_OUT) * D_DIM + d];
        Bcat[e] = v;
    } else {
        // ---- cnorm + cadj fold + pad zeros ----
        int wave = tid >> 6, lane = tid & 63;
        int k = (bid - 1856) * 4 + wave;
        const float* row = cent + (size_t)k * D_DIM;
        float s = 0.f, t = 0.f;
#pragma unroll
        for (int j = 0; j < 8; ++j) {
            float c = row[lane + 64 * j];
            float b = benc[lane + 64 * j];
            s += c * c; t += b * c;
        }
#pragma unroll
        for (int off = 32; off; off >>= 1) { s += __shfl_down(s, off); t += __shfl_down(t, off); }
        const int nt = k >> 7, cl = k & 127;
        const size_t tb = (size_t)(nt * 3 + 2) * 4096;   // kt=2 holds k=64..95
        if (lane < 14)   // zero pad rows f=82..95
            Gbt[tb + frag32_addr(cl, 18 + lane)] = 0;
        if (lane == 0) {
            cnorm[k] = s;
            float v = -0.5f * (s - 2.0f * t);
            unsigned short h = f2bf(v);
            unsigned short l = f2bf(v - bf2f(h));
            Gbt[tb + frag32_addr(cl, 16)] = h;   // f=80
            Gbt[tb + frag32_addr(cl, 17)] = l;   // f=81
        }
    }
}

// ============================ kernel 2: fused dec + G GEMM (f32 VALU, d-split) ============================
__global__ __launch_bounds__(384) void k_cgemm2(
    const float* __restrict__ cent, const float* __restrict__ Bcat,
    const float* __restrict__ bdec, unsigned short* __restrict__ Gbt,
    float* __restrict__ dec) {
    __shared__ float pacc[192][4];   // dh=1 partials, 3 KB
    const int tid = threadIdx.x;
    const int j = tid % 192;
    const int dh = tid / 192;
    const int k0 = blockIdx.x * 4;
    float a0 = 0.f, a1 = 0.f, a2 = 0.f, a3 = 0.f;
    if (j < JTOT) {
        const float* c0 = cent + (size_t)k0 * D_DIM + dh * 256;
        const float* bp = Bcat + (size_t)dh * 256 * JTOT + j;
#pragma unroll 4
        for (int d = 0; d < 256; ++d) {
            float b  = bp[d * JTOT];
            a0 += c0[d] * b;
            a1 += c0[D_DIM + d] * b;
            a2 += c0[2 * D_DIM + d] * b;
            a3 += c0[3 * D_DIM + d] * b;
        }
        if (dh == 1) { pacc[j][0] = a0; pacc[j][1] = a1; pacc[j][2] = a2; pacc[j][3] = a3; }
    }
    __syncthreads();
    if (dh == 0 && j < JTOT) {
        a0 += pacc[j][0]; a1 += pacc[j][1]; a2 += pacc[j][2]; a3 += pacc[j][3];
        float a[4] = { a0, a1, a2, a3 };
        if (j < F_OUT) {
            float bd = bdec[j];
#pragma unroll
            for (int c = 0; c < 4; ++c)
                dec[(size_t)(k0 + c) * F_OUT + j] = a[c] + bd;
        } else {
            int f = j - F_OUT;   // 0..79
#pragma unroll
            for (int c = 0; c < 4; ++c) {
                int k = k0 + c;
                Gbt[(size_t)((k >> 7) * 3 + (f >> 5)) * 4096 + frag32_addr(k & 127, f & 31)]
                    = f2bf(a[c]);
            }
        }
    }
}

// ============================ distance + per-token argmax + candidates ============================
// 1024 blocks = (256 mt) x (4 nq); 512 thr = 4 token-groups x 2 centroid-halves.
// XCD-chunked bijective swizzle (1024 % 8 == 0): each XCD owns 128 consecutive
// logical blocks -> one mt's 4 nq-blocks share an XCD's L2 (xbt fetched once).
__global__ __launch_bounds__(512) void k_dist3(
    const unsigned short* __restrict__ xbt, const unsigned short* __restrict__ Gbt,
    char* __restrict__ lists) {
    __shared__ unsigned short Bs[2][12288];   // 48 KB dbuf
    __shared__ int cnt[128];
    __shared__ unsigned mxk[128];

    const int tid = threadIdx.x;
    const int swz = (blockIdx.x & 7) * 128 + (blockIdx.x >> 3);   // XCD-chunked
    const int mt = swz >> 2, nq = swz & 3;
    const int lane = tid & 63;
    const int wave = tid >> 6;
    const int tg = wave >> 1;       // token group: tokens tg*32..+31
    const int ch = wave & 1;        // centroid half: rows ch*64..+63 of tile
    const int col = lane & 31;
    const int hi = lane >> 5;

    if (tid < 128) { cnt[tid] = 0; mxk[tid] = 0u; }

    bf16x8 bfr[6];
    const unsigned short* Ab = xbt + (size_t)mt * 12288;
#pragma unroll
    for (int kc = 0; kc < 6; ++kc)
        bfr[kc] = *(const bf16x8*)&Ab[(kc >> 1) * 4096 + (tg * 2 + (kc & 1)) * 512 + lane * 8];

    const int woff = (tid & ~63) * 8;
    const unsigned short* Gq = Gbt + (size_t)nq * 4 * 12288;
#pragma unroll
    for (int q = 0; q < 3; ++q)
        gll16(Gq + q * 4096 + tid * 8, &Bs[0][0] + q * 4096 + woff);

    float rmax = -3.4e38f;
    int cur = 0;
    for (int t4 = 0; t4 < 4; ++t4) {
        __syncthreads();
        if (t4 + 1 < 4) {
#pragma unroll
            for (int q = 0; q < 3; ++q)
                gll16(Gq + (size_t)(t4 + 1) * 12288 + q * 4096 + tid * 8,
                      &Bs[cur ^ 1][0] + q * 4096 + woff);
        }
        const unsigned short* B = &Bs[cur][0];
        fx16 acc[2];
#pragma unroll
        for (int u = 0; u < 2; ++u)
#pragma unroll
            for (int r = 0; r < 16; ++r) acc[u][r] = 0.f;
#pragma unroll
        for (int kc = 0; kc < 6; ++kc) {
#pragma unroll
            for (int u = 0; u < 2; ++u) {
                bf16x8 a = *(const bf16x8*)&B[(kc >> 1) * 4096
                             + ((ch * 2 + u) * 2 + (kc & 1)) * 512 + lane * 8];
                acc[u] = __builtin_amdgcn_mfma_f32_32x32x16_bf16(a, bfr[kc], acc[u], 0, 0, 0);
            }
        }
        float m = acc[0][0];
#pragma unroll
        for (int r = 1; r < 16; ++r) m = fmaxf(m, acc[0][r]);
#pragma unroll
        for (int r = 0; r < 16; ++r) m = fmaxf(m, acc[1][r]);
        m = fmaxf(m, __shfl_xor(m, 32));
        rmax = fmaxf(rmax, m);
        const float th = rmax - M2;
        const int tk = tg * 32 + col;
        char* qrec = lists + (size_t)(mt * 128 + tk) * TREC + nq * QREC;
#pragma unroll
        for (int u = 0; u < 2; ++u)
#pragma unroll
            for (int r = 0; r < 16; ++r) {
                float v = acc[u][r];
                if (v >= th) {
                    int slot = atomicAdd(&cnt[tk], 1);
                    if (slot < QSLOTS) {
                        uint2 e;
                        e.x = __float_as_uint(v);
                        e.y = (unsigned)((nq * 4 + t4) * 128 + (ch * 2 + u) * 32
                                         + (r & 3) + 8 * (r >> 2) + 4 * hi);
                        *(uint2*)(qrec + 8 + slot * 8) = e;
                    }
                }
            }
        cur ^= 1;
    }
    if (lane < 32) atomicMax(&mxk[tg * 32 + lane], fkey(rmax));
    __syncthreads();
    if (tid < 128) {
        uint2 h;
        h.x = (unsigned)cnt[tid];
        h.y = __float_as_uint(keyf(mxk[tid]));
        *(uint2*)(lists + (size_t)(mt * 128 + tid) * TREC + nq * QREC) = h;
    }
}

// ============================ merge (1 token/wave) + exact-refine + decode gather ============================
__global__ __launch_bounds__(256) void k_merge4(
    const char* __restrict__ lists, const float* __restrict__ cnorm,
    const float* __restrict__ cent, const float* __restrict__ x,
    const float* __restrict__ Wenc, const float* __restrict__ benc,
    const float* __restrict__ dec, float* __restrict__ out) {
    const int lane = threadIdx.x & 63;
    const int token = blockIdx.x * 4 + (threadIdx.x >> 6);   // 8192 blocks x 4 waves
    const char* base = lists + (size_t)token * TREC;
    uint4 w4 = make_uint4(0u, 0u, 0u, 0u);
    if (lane < 50) w4 = *(const uint4*)(base + lane * 16);
    const int   c0 = __shfl((int)w4.x, 0),  c1 = __shfl((int)w4.z, 12);
    const int   c2 = __shfl((int)w4.x, 25), c3 = __shfl((int)w4.z, 37);
    const float m0 = __uint_as_float((unsigned)__shfl((int)w4.y, 0));
    const float m1 = __uint_as_float((unsigned)__shfl((int)w4.w, 12));
    const float m2 = __uint_as_float((unsigned)__shfl((int)w4.y, 25));
    const float m3 = __uint_as_float((unsigned)__shfl((int)w4.w, 37));
    const float gm = fmaxf(fmaxf(m0, m1), fmaxf(m2, m3));
    const float th = gm - M2;
    const bool ovf = (c0 > QSLOTS) || (c1 > QSLOTS) || (c2 > QSLOTS) || (c3 > QSLOTS);
    const int q0c = c0 < QSLOTS ? c0 : QSLOTS, q1c = c1 < QSLOTS ? c1 : QSLOTS;
    const int q2c = c2 < QSLOTS ? c2 : QSLOTS, q3c = c3 < QSLOTS ? c3 : QSLOTS;
    bool cd[2];
#pragma unroll
    for (int rr = 0; rr < 2; ++rr) {
        int t = lane * 2 + rr;
        int q = t / 25, s = t - q * 25;
        int cq = (q == 0) ? q0c : (q == 1) ? q1c : (q == 2) ? q2c : q3c;
        float v = __uint_as_float(rr ? w4.z : w4.x);
        cd[rr] = (lane < 50) && (s >= 1) && (s - 1 < cq) && (v >= th);
    }
    unsigned long long b0 = __ballot(cd[0]);
    unsigned long long b1 = __ballot(cd[1]);
    int ns = __popcll(b0) + __popcll(b1);
    int ans;
    if (!ovf && ns == 1) {
        if (b0) ans = __shfl((int)w4.y, __ffsll(b0) - 1);
        else    ans = __shfl((int)w4.w, __ffsll(b1) - 1);
    } else {
        float z8[8];
#pragma unroll
        for (int j = 0; j < 8; ++j) z8[j] = benc[lane * 8 + j];
        const float* xr = x + (size_t)token * F_IN;
        const float* wp = Wenc + lane * 8;
        for (int f = 0; f < F_IN; ++f) {
            float xf = xr[f];
            fx4 w0 = *(const fx4*)(wp + (size_t)f * D_DIM);
            fx4 w1 = *(const fx4*)(wp + (size_t)f * D_DIM + 4);
            z8[0] += xf * w0.x; z8[1] += xf * w0.y; z8[2] += xf * w0.z; z8[3] += xf * w0.w;
            z8[4] += xf * w1.x; z8[5] += xf * w1.y; z8[6] += xf * w1.z; z8[7] += xf * w1.w;
        }
        float bd = 1e30f; int bn = 0x7FFFFFFF;
        auto exact1 = [&](int ci) {
            const float* cr = cent + (size_t)ci * D_DIM + lane * 8;
            fx4 cc0 = *(const fx4*)cr, cc1 = *(const fx4*)(cr + 4);
            float dp = z8[0] * cc0.x + z8[1] * cc0.y + z8[2] * cc0.z + z8[3] * cc0.w
                     + z8[4] * cc1.x + z8[5] * cc1.y + z8[6] * cc1.z + z8[7] * cc1.w;
#pragma unroll
            for (int off = 1; off < 64; off <<= 1) dp += __shfl_xor(dp, off);
            float de = cnorm[ci] - 2.0f * dp;
            if (de < bd || (de == bd && ci < bn)) { bd = de; bn = ci; }
        };
        unsigned long long m = b0;
        while (m) { int src = __ffsll(m) - 1; m &= m - 1; exact1(__shfl((int)w4.y, src)); }
        m = b1;
        while (m) { int src = __ffsll(m) - 1; m &= m - 1; exact1(__shfl((int)w4.w, src)); }
        if (ovf) {
#pragma unroll
            for (int q = 0; q < 4; ++q) {
                int cf = (q == 0) ? c0 : (q == 1) ? c1 : (q == 2) ? c2 : c3;
                if (cf > QSLOTS)
                    for (int n0 = 0; n0 < 512; ++n0) exact1(q * 512 + n0);
            }
        }
        ans = bn;
    }
    const float* dr = dec + (size_t)ans * F_OUT;
    float* orow = out + (size_t)token * F_OUT;
    orow[lane] = dr[lane];
    if (lane < F_OUT - 64) orow[64 + lane] = dr[64 + lane];
}

// ============================ fallback path (round-1, known-good) ============================
__global__ void k_transpose(const float* __restrict__ cent, float* __restrict__ centT) {
    __shared__ float tile[64][65];
    int kb = blockIdx.x * 64, db = blockIdx.y * 64;
    int lx = threadIdx.x & 63, ly = threadIdx.x >> 6;
#pragma unroll
    for (int i = 0; i < 16; ++i) {
        int row = ly + i * 4;
        tile[row][lx] = cent[(size_t)(kb + row) * D_DIM + db + lx];
    }
    __syncthreads();
#pragma unroll
    for (int i = 0; i < 16; ++i) {
        int row = ly + i * 4;
        centT[(size_t)(db + row) * K_CENT + kb + lx] = tile[lx][row];
    }
}

__global__ void k_cnorm(const float* __restrict__ cent, float* __restrict__ cnorm) {
    int wave = threadIdx.x >> 6, lane = threadIdx.x & 63;
    int k = blockIdx.x * 4 + wave;
    const float* row = cent + (size_t)k * D_DIM;
    float s = 0.f;
#pragma unroll
    for (int j = 0; j < 8; ++j) { float v = row[lane + 64 * j]; s += v * v; }
#pragma unroll
    for (int off = 32; off; off >>= 1) s += __shfl_down(s, off);
    if (lane == 0) cnorm[k] = s;
}

__global__ void k_dec(const float* __restrict__ cent, const float* __restrict__ Wdec,
                      const float* __restrict__ bdec, float* __restrict__ dec) {
    __shared__ float cs[D_DIM];
    int k = blockIdx.x;
    for (int d = threadIdx.x; d < D_DIM; d += blockDim.x) cs[d] = cent[(size_t)k * D_DIM + d];
    __syncthreads();
    int f = threadIdx.x;
    if (f < F_OUT) {
        float a0 = 0.f, a1 = 0.f, a2 = 0.f, a3 = 0.f;
#pragma unroll 4
        for (int d = 0; d < D_DIM; d += 4) {
            a0 += cs[d + 0] * Wdec[(d + 0) * F_OUT + f];
            a1 += cs[d + 1] * Wdec[(d + 1) * F_OUT + f];
            a2 += cs[d + 2] * Wdec[(d + 2) * F_OUT + f];
            a3 += cs[d + 3] * Wdec[(d + 3) * F_OUT + f];
        }
        dec[(size_t)k * F_OUT + f] = a0 + a1 + a2 + a3 + bdec[f];
    }
}

__global__ void k_out(const float* __restrict__ dec, const int* __restrict__ idx,
                      float* __restrict__ out) {
    int e0 = blockIdx.x * 2560;
#pragma unroll
    for (int r = 0; r < 10; ++r) {
        int e = e0 + threadIdx.x + r * 256;
        int n = e / F_OUT, f = e - n * F_OUT;
        out[e] = dec[(size_t)idx[n] * F_OUT + f];
    }
}

__global__ __launch_bounds__(256) void k_main(
    const float* __restrict__ x, const float* __restrict__ Wenc,
    const float* __restrict__ benc, const float* __restrict__ centT,
    const float* __restrict__ cnorm, int* __restrict__ idxOut) {
    __shared__ float xs[TM * F_IN];
    __shared__ float zs[TM][D_DIM];
    float* pv = &zs[0][0];
    int*   pi = (int*)(&zs[0][0] + 256 * TM);
    const int tid = threadIdx.x;
    const int tok0 = blockIdx.x * TM;
    for (int e = tid; e < TM * F_IN; e += 256) xs[e] = x[(size_t)tok0 * F_IN + e];
    __syncthreads();
    {
        float acc0[TM], acc1[TM];
#pragma unroll
        for (int t = 0; t < TM; ++t) { acc0[t] = 0.f; acc1[t] = 0.f; }
        const float2 b2 = ((const float2*)benc)[tid];
#pragma unroll 4
        for (int f4 = 0; f4 < F_IN; f4 += 4) {
            float2 w0 = ((const float2*)(Wenc + (size_t)(f4 + 0) * D_DIM))[tid];
            float2 w1 = ((const float2*)(Wenc + (size_t)(f4 + 1) * D_DIM))[tid];
            float2 w2 = ((const float2*)(Wenc + (size_t)(f4 + 2) * D_DIM))[tid];
            float2 w3 = ((const float2*)(Wenc + (size_t)(f4 + 3) * D_DIM))[tid];
#pragma unroll
            for (int t = 0; t < TM; ++t) {
                float4 xv = *(const float4*)&xs[t * F_IN + f4];
                acc0[t] += xv.x * w0.x + xv.y * w1.x + xv.z * w2.x + xv.w * w3.x;
                acc1[t] += xv.x * w0.y + xv.y * w1.y + xv.z * w2.y + xv.w * w3.y;
            }
        }
#pragma unroll
        for (int t = 0; t < TM; ++t)
            *(float2*)&zs[t][2 * tid] = make_float2(acc0[t] + b2.x, acc1[t] + b2.y);
    }
    __syncthreads();
    float minv[TM]; int mini[TM];
#pragma unroll
    for (int t = 0; t < TM; ++t) { minv[t] = 3.4e38f; mini[t] = 0; }
    for (int iter = 0; iter < 2; ++iter) {
        float acc[4][TM];
#pragma unroll
        for (int j = 0; j < 4; ++j)
#pragma unroll
            for (int t = 0; t < TM; ++t) acc[j][t] = 0.f;
        const int cbase = iter * 1024 + tid;
        for (int d4 = 0; d4 < D_DIM; d4 += 4) {
            float cv[4][4];
#pragma unroll
            for (int dd = 0; dd < 4; ++dd) {
                const float* cp = centT + (size_t)(d4 + dd) * K_CENT + cbase;
                cv[dd][0] = cp[0]; cv[dd][1] = cp[256]; cv[dd][2] = cp[512]; cv[dd][3] = cp[768];
            }
#pragma unroll
            for (int t = 0; t < TM; ++t) {
                float4 zv = *(const float4*)&zs[t][d4];
#pragma unroll
                for (int j = 0; j < 4; ++j)
                    acc[j][t] += zv.x * cv[0][j] + zv.y * cv[1][j] + zv.z * cv[2][j] + zv.w * cv[3][j];
            }
        }
#pragma unroll
        for (int j = 0; j < 4; ++j) {
            int c = cbase + j * 256;
            float cn = cnorm[c];
#pragma unroll
            for (int t = 0; t < TM; ++t) {
                float dist = cn - 2.f * acc[j][t];
                if (dist < minv[t]) { minv[t] = dist; mini[t] = c; }
            }
        }
    }
    __syncthreads();
#pragma unroll
    for (int t = 0; t < TM; ++t) { pv[tid * TM + t] = minv[t]; pi[tid * TM + t] = mini[t]; }
    __syncthreads();
    {
        int t = tid & 15, g = tid >> 4;
        float bv = 3.4e38f; int bi = 0x7fffffff;
        for (int j = 0; j < 16; ++j) {
            int r2 = g + 16 * j;
            float vv = pv[r2 * TM + t]; int i2 = pi[r2 * TM + t];
            if (vv < bv || (vv == bv && i2 < bi)) { bv = vv; bi = i2; }
        }
        pv[g * TM + t] = bv; pi[g * TM + t] = bi;
    }
    __syncthreads();
    if (tid < TM) {
        int t = tid;
        float bv = 3.4e38f; int bi = 0x7fffffff;
        for (int g = 0; g < 16; ++g) {
            float vv = pv[g * TM + t]; int i2 = pi[g * TM + t];
            if (vv < bv || (vv == bv && i2 < bi)) { bv = vv; bi = i2; }
        }
        idxOut[tok0 + t] = bi;
    }
}

// ============================ launch ============================
extern "C" void kernel_launch(void* const* d_in, const int* in_sizes, int n_in,
                              void* d_out, int out_size, void* d_ws, size_t ws_size,
                              hipStream_t stream) {
    const float* x    = (const float*)d_in[0];
    const float* Wenc = (const float*)d_in[1];
    const float* benc = (const float*)d_in[2];
    const float* cent = (const float*)d_in[3];
    const float* Wdec = (const float*)d_in[4];
    const float* bdec = (const float*)d_in[5];
    float* out = (float*)d_out;

    const size_t L_B  = (size_t)N_TOK * TREC;            // 26214400 candidate lists
    const size_t XB_B = (size_t)N_TOK * KP * 2;          //  6291456 xbt
    const size_t GB_B = (size_t)K_CENT * KP * 2;         //   393216 Gbt
    const size_t N_B  = (size_t)K_CENT * 4;              //     8192 cnorm
    const size_t D_B  = (size_t)K_CENT * F_OUT * 4;      //   655360 dec
    const size_t BC_B = (size_t)D_DIM * JTOT * 4;        //   327680 Bcat
    const size_t NEED = L_B + XB_B + GB_B + N_B + D_B + BC_B;

    if (ws_size >= NEED) {
        char* w = (char*)d_ws;
        char*           lists = w;                            w += L_B;
        unsigned short* xbt   = (unsigned short*)w;           w += XB_B;
        unsigned short* Gbt   = (unsigned short*)w;           w += GB_B;
        float*          cnorm = (float*)w;                    w += N_B;
        float*          dec   = (float*)w;                    w += D_B;
        float*          Bcat  = (float*)w;

        k_prep1<<<2368, 256, 0, stream>>>(x, Wenc, Wdec, cent, benc,
                                          xbt, Bcat, cnorm, Gbt);
        k_cgemm2<<<K_CENT / 4, 384, 0, stream>>>(cent, Bcat, bdec, Gbt, dec);
        k_dist3<<<1024, 512, 0, stream>>>(xbt, Gbt, lists);
        k_merge4<<<N_TOK / 4, 256, 0, stream>>>(lists, cnorm, cent, x, Wenc, benc, dec, out);
    } else {
        float* centT = (float*)d_ws;
        float* cnorm = centT + (size_t)D_DIM * K_CENT;
        float* dec   = cnorm + K_CENT;
        int*   idx   = (int*)(dec + (size_t)K_CENT * F_OUT);
        k_transpose<<<dim3(K_CENT / 64, D_DIM / 64), 256, 0, stream>>>(cent, centT);
        k_cnorm<<<K_CENT / 4, 256, 0, stream>>>(cent, cnorm);
        k_dec<<<K_CENT, 128, 0, stream>>>(cent, Wdec, bdec, dec);
        k_main<<<N_TOK / TM, 256, 0, stream>>>(x, Wenc, benc, centT, cnorm, idx);
        k_out<<<N_TOK * F_OUT / 2560, 256, 0, stream>>>(dec, idx, out);
    }
}

// Round 17
// 96.689 us; speedup vs baseline: 1.1851x; 1.0325x over previous
//
#include <hip/hip_runtime.h>
#include <hip/hip_bf16.h>

#define N_TOK  32768
#define F_IN   80
#define D_DIM  512
#define K_CENT 2048
#define F_OUT  80
#define TM     16
#define KP     96
#define M2     0.5f      // margin in acc units (dist = -2*acc)
#define QSLOTS 24
#define QREC   200       // 8B header {cnt,max} + 24 * 8B records
#define TREC   800       // 4 quarters per token (100 x 8B flat slots)
#define JTOT   160       // Bcat width: 80 dec | 80 G

typedef __attribute__((ext_vector_type(8)))  short bf16x8;
typedef __attribute__((ext_vector_type(4)))  float fx4;
typedef __attribute__((ext_vector_type(16))) float fx16;

#define AS3 __attribute__((address_space(3)))
#define AS1 __attribute__((address_space(1)))

__device__ inline unsigned short f2bf(float f) {
    unsigned u = __float_as_uint(f);
    return (unsigned short)((u + 0x7FFFu + ((u >> 16) & 1u)) >> 16);
}
__device__ inline float bf2f(unsigned short h) {
    return __uint_as_float((unsigned)h << 16);
}

__device__ inline void gll16(const unsigned short* g, unsigned short* l) {
    __builtin_amdgcn_global_load_lds((const AS1 unsigned*)g, (AS3 unsigned*)l, 16, 0, 0);
}

__device__ inline unsigned fkey(float f) {
    unsigned b = __float_as_uint(f);
    return b ^ ((b >> 31) ? 0xFFFFFFFFu : 0x80000000u);
}
__device__ inline float keyf(unsigned k) {
    unsigned b = k ^ ((k & 0x80000000u) ? 0x80000000u : 0xFFFFFFFFu);
    return __uint_as_float(b);
}

// 32x32x16 fragment-linear tile [128 rows][32 k] (dist operands)
__device__ inline size_t frag32_addr(int row, int k) {
    int sub = (row >> 5) * 2 + ((k >> 4) & 1);
    int L = (row & 31) + ((k >> 3) & 1) * 32;
    return (size_t)sub * 512 + L * 8 + (k & 7);
}

// ============================ kernel 1: xbt + Bcat + cnorm/cadj-fold ============================
__global__ __launch_bounds__(256) void k_prep1(
    const float* __restrict__ x, const float* __restrict__ Wenc,
    const float* __restrict__ Wdec, const float* __restrict__ cent,
    const float* __restrict__ benc,
    unsigned short* __restrict__ xbt, float* __restrict__ Bcat,
    float* __restrict__ cnorm, unsigned short* __restrict__ Gbt) {
    const int bid = blockIdx.x, tid = threadIdx.x;
    if (bid < 1536) {
        // ---- xbt (frag32, dims 80,81 = 1.0 for cadj fold, 82..95 = 0) ----
        int o = bid * 256 + tid;    // 393216 octets
        int m = o / 12;
        int ko = (o - m * 12) * 8;
        unsigned short u[8];
        if (ko < F_IN) {
            const float* src = x + (size_t)m * F_IN + ko;
            float4 v0 = *(const float4*)src;
            float4 v1 = *(const float4*)(src + 4);
            u[0]=f2bf(v0.x); u[1]=f2bf(v0.y); u[2]=f2bf(v0.z); u[3]=f2bf(v0.w);
            u[4]=f2bf(v1.x); u[5]=f2bf(v1.y); u[6]=f2bf(v1.z); u[7]=f2bf(v1.w);
        } else if (ko == 80) {
            u[0] = 0x3F80; u[1] = 0x3F80;
#pragma unroll
            for (int j = 2; j < 8; ++j) u[j] = 0;
        } else {
#pragma unroll
            for (int j = 0; j < 8; ++j) u[j] = 0;
        }
        int mt = m >> 7, kt = ko >> 5, row = m & 127, kl = ko & 31;
        uint4 p;
        p.x = (unsigned)u[0] | ((unsigned)u[1] << 16);
        p.y = (unsigned)u[2] | ((unsigned)u[3] << 16);
        p.z = (unsigned)u[4] | ((unsigned)u[5] << 16);
        p.w = (unsigned)u[6] | ((unsigned)u[7] << 16);
        *(uint4*)&xbt[(size_t)(mt * 3 + kt) * 4096 + frag32_addr(row, kl)] = p;
    } else if (bid < 1856) {
        // ---- Bcat ----
        int e = (bid - 1536) * 256 + tid;      // 81920 elems
        int d = e / JTOT, j = e - d * JTOT;
        float v = (j < F_OUT) ? Wdec[(size_t)d * F_OUT + j]
                              : Wenc[(size_t)(j - F_OUT) * D_DIM + d];
        Bcat[e] = v;
    } else {
        // ---- cnorm + cadj fold + pad zeros ----
        int wave = tid >> 6, lane = tid & 63;
        int k = (bid - 1856) * 4 + wave;
        const float* row = cent + (size_t)k * D_DIM;
        float s = 0.f, t = 0.f;
#pragma unroll
        for (int j = 0; j < 8; ++j) {
            float c = row[lane + 64 * j];
            float b = benc[lane + 64 * j];
            s += c * c; t += b * c;
        }
#pragma unroll
        for (int off = 32; off; off >>= 1) { s += __shfl_down(s, off); t += __shfl_down(t, off); }
        const int nt = k >> 7, cl = k & 127;
        const size_t tb = (size_t)(nt * 3 + 2) * 4096;   // kt=2 holds k=64..95
        if (lane < 14)   // zero pad rows f=82..95
            Gbt[tb + frag32_addr(cl, 18 + lane)] = 0;
        if (lane == 0) {
            cnorm[k] = s;
            float v = -0.5f * (s - 2.0f * t);
            unsigned short h = f2bf(v);
            unsigned short l = f2bf(v - bf2f(h));
            Gbt[tb + frag32_addr(cl, 16)] = h;   // f=80
            Gbt[tb + frag32_addr(cl, 17)] = l;   // f=81
        }
    }
}

// ============================ kernel 2: fused dec + G GEMM (f32 VALU, d-split) ============================
__global__ __launch_bounds__(384) void k_cgemm2(
    const float* __restrict__ cent, const float* __restrict__ Bcat,
    const float* __restrict__ bdec, unsigned short* __restrict__ Gbt,
    float* __restrict__ dec) {
    __shared__ float pacc[192][4];   // dh=1 partials, 3 KB
    const int tid = threadIdx.x;
    const int j = tid % 192;
    const int dh = tid / 192;
    const int k0 = blockIdx.x * 4;
    float a0 = 0.f, a1 = 0.f, a2 = 0.f, a3 = 0.f;
    if (j < JTOT) {
        const float* c0 = cent + (size_t)k0 * D_DIM + dh * 256;
        const float* bp = Bcat + (size_t)dh * 256 * JTOT + j;
#pragma unroll 4
        for (int d = 0; d < 256; ++d) {
            float b  = bp[d * JTOT];
            a0 += c0[d] * b;
            a1 += c0[D_DIM + d] * b;
            a2 += c0[2 * D_DIM + d] * b;
            a3 += c0[3 * D_DIM + d] * b;
        }
        if (dh == 1) { pacc[j][0] = a0; pacc[j][1] = a1; pacc[j][2] = a2; pacc[j][3] = a3; }
    }
    __syncthreads();
    if (dh == 0 && j < JTOT) {
        a0 += pacc[j][0]; a1 += pacc[j][1]; a2 += pacc[j][2]; a3 += pacc[j][3];
        float a[4] = { a0, a1, a2, a3 };
        if (j < F_OUT) {
            float bd = bdec[j];
#pragma unroll
            for (int c = 0; c < 4; ++c)
                dec[(size_t)(k0 + c) * F_OUT + j] = a[c] + bd;
        } else {
            int f = j - F_OUT;   // 0..79
#pragma unroll
            for (int c = 0; c < 4; ++c) {
                int k = k0 + c;
                Gbt[(size_t)((k >> 7) * 3 + (f >> 5)) * 4096 + frag32_addr(k & 127, f & 31)]
                    = f2bf(a[c]);
            }
        }
    }
}

// ============================ distance + per-token argmax + candidates ============================
// 1024 blocks = (256 mt) x (4 nq); 512 thr = 4 token-groups x 2 centroid-halves.
// SINGLE-buffered 24 KB stage (LDS ~25.6 KB) -> 4 blocks/CU resident: inter-block
// TLP hides each block's stage-drain (m114). XCD-chunked swizzle for L2 locality.
__global__ __launch_bounds__(512) void k_dist3(
    const unsigned short* __restrict__ xbt, const unsigned short* __restrict__ Gbt,
    char* __restrict__ lists) {
    __shared__ unsigned short Bs[12288];      // 24 KB single buffer
    __shared__ int cnt[128];
    __shared__ unsigned mxk[128];

    const int tid = threadIdx.x;
    const int swz = (blockIdx.x & 7) * 128 + (blockIdx.x >> 3);   // XCD-chunked
    const int mt = swz >> 2, nq = swz & 3;
    const int lane = tid & 63;
    const int wave = tid >> 6;
    const int tg = wave >> 1;       // token group: tokens tg*32..+31
    const int ch = wave & 1;        // centroid half: rows ch*64..+63 of tile
    const int col = lane & 31;
    const int hi = lane >> 5;

    if (tid < 128) { cnt[tid] = 0; mxk[tid] = 0u; }

    bf16x8 bfr[6];
    const unsigned short* Ab = xbt + (size_t)mt * 12288;
#pragma unroll
    for (int kc = 0; kc < 6; ++kc)
        bfr[kc] = *(const bf16x8*)&Ab[(kc >> 1) * 4096 + (tg * 2 + (kc & 1)) * 512 + lane * 8];

    const int woff = (tid & ~63) * 8;
    const unsigned short* Gq = Gbt + (size_t)nq * 4 * 12288;

    float rmax = -3.4e38f;
    for (int t4 = 0; t4 < 4; ++t4) {
        // stage tile t4 into the single buffer
#pragma unroll
        for (int q = 0; q < 3; ++q)
            gll16(Gq + (size_t)t4 * 12288 + q * 4096 + tid * 8, &Bs[0] + q * 4096 + woff);
        __syncthreads();   // drain staging (and, on t4>0, ordering after prior compute)
        fx16 acc[2];
#pragma unroll
        for (int u = 0; u < 2; ++u)
#pragma unroll
            for (int r = 0; r < 16; ++r) acc[u][r] = 0.f;
#pragma unroll
        for (int kc = 0; kc < 6; ++kc) {
#pragma unroll
            for (int u = 0; u < 2; ++u) {
                bf16x8 a = *(const bf16x8*)&Bs[(kc >> 1) * 4096
                             + ((ch * 2 + u) * 2 + (kc & 1)) * 512 + lane * 8];
                acc[u] = __builtin_amdgcn_mfma_f32_32x32x16_bf16(a, bfr[kc], acc[u], 0, 0, 0);
            }
        }
        float m = acc[0][0];
#pragma unroll
        for (int r = 1; r < 16; ++r) m = fmaxf(m, acc[0][r]);
#pragma unroll
        for (int r = 0; r < 16; ++r) m = fmaxf(m, acc[1][r]);
        m = fmaxf(m, __shfl_xor(m, 32));
        rmax = fmaxf(rmax, m);
        const float th = rmax - M2;
        const int tk = tg * 32 + col;
        char* qrec = lists + (size_t)(mt * 128 + tk) * TREC + nq * QREC;
#pragma unroll
        for (int u = 0; u < 2; ++u)
#pragma unroll
            for (int r = 0; r < 16; ++r) {
                float v = acc[u][r];
                if (v >= th) {
                    int slot = atomicAdd(&cnt[tk], 1);
                    if (slot < QSLOTS) {
                        uint2 e;
                        e.x = __float_as_uint(v);
                        e.y = (unsigned)((nq * 4 + t4) * 128 + (ch * 2 + u) * 32
                                         + (r & 3) + 8 * (r >> 2) + 4 * hi);
                        *(uint2*)(qrec + 8 + slot * 8) = e;
                    }
                }
            }
        __syncthreads();   // all reads of Bs done before next round's staging overwrites
    }
    if (lane < 32) atomicMax(&mxk[tg * 32 + lane], fkey(rmax));
    __syncthreads();
    if (tid < 128) {
        uint2 h;
        h.x = (unsigned)cnt[tid];
        h.y = __float_as_uint(keyf(mxk[tid]));
        *(uint2*)(lists + (size_t)(mt * 128 + tid) * TREC + nq * QREC) = h;
    }
}

// ============================ merge (1 token/wave) + exact-refine + decode gather ============================
__global__ __launch_bounds__(256) void k_merge4(
    const char* __restrict__ lists, const float* __restrict__ cnorm,
    const float* __restrict__ cent, const float* __restrict__ x,
    const float* __restrict__ Wenc, const float* __restrict__ benc,
    const float* __restrict__ dec, float* __restrict__ out) {
    const int lane = threadIdx.x & 63;
    const int token = blockIdx.x * 4 + (threadIdx.x >> 6);   // 8192 blocks x 4 waves
    const char* base = lists + (size_t)token * TREC;
    uint4 w4 = make_uint4(0u, 0u, 0u, 0u);
    if (lane < 50) w4 = *(const uint4*)(base + lane * 16);
    const int   c0 = __shfl((int)w4.x, 0),  c1 = __shfl((int)w4.z, 12);
    const int   c2 = __shfl((int)w4.x, 25), c3 = __shfl((int)w4.z, 37);
    const float m0 = __uint_as_float((unsigned)__shfl((int)w4.y, 0));
    const float m1 = __uint_as_float((unsigned)__shfl((int)w4.w, 12));
    const float m2 = __uint_as_float((unsigned)__shfl((int)w4.y, 25));
    const float m3 = __uint_as_float((unsigned)__shfl((int)w4.w, 37));
    const float gm = fmaxf(fmaxf(m0, m1), fmaxf(m2, m3));
    const float th = gm - M2;
    const bool ovf = (c0 > QSLOTS) || (c1 > QSLOTS) || (c2 > QSLOTS) || (c3 > QSLOTS);
    const int q0c = c0 < QSLOTS ? c0 : QSLOTS, q1c = c1 < QSLOTS ? c1 : QSLOTS;
    const int q2c = c2 < QSLOTS ? c2 : QSLOTS, q3c = c3 < QSLOTS ? c3 : QSLOTS;
    bool cd[2];
#pragma unroll
    for (int rr = 0; rr < 2; ++rr) {
        int t = lane * 2 + rr;
        int q = t / 25, s = t - q * 25;
        int cq = (q == 0) ? q0c : (q == 1) ? q1c : (q == 2) ? q2c : q3c;
        float v = __uint_as_float(rr ? w4.z : w4.x);
        cd[rr] = (lane < 50) && (s >= 1) && (s - 1 < cq) && (v >= th);
    }
    unsigned long long b0 = __ballot(cd[0]);
    unsigned long long b1 = __ballot(cd[1]);
    int ns = __popcll(b0) + __popcll(b1);
    int ans;
    if (!ovf && ns == 1) {
        if (b0) ans = __shfl((int)w4.y, __ffsll(b0) - 1);
        else    ans = __shfl((int)w4.w, __ffsll(b1) - 1);
    } else {
        float z8[8];
#pragma unroll
        for (int j = 0; j < 8; ++j) z8[j] = benc[lane * 8 + j];
        const float* xr = x + (size_t)token * F_IN;
        const float* wp = Wenc + lane * 8;
        for (int f = 0; f < F_IN; ++f) {
            float xf = xr[f];
            fx4 w0 = *(const fx4*)(wp + (size_t)f * D_DIM);
            fx4 w1 = *(const fx4*)(wp + (size_t)f * D_DIM + 4);
            z8[0] += xf * w0.x; z8[1] += xf * w0.y; z8[2] += xf * w0.z; z8[3] += xf * w0.w;
            z8[4] += xf * w1.x; z8[5] += xf * w1.y; z8[6] += xf * w1.z; z8[7] += xf * w1.w;
        }
        float bd = 1e30f; int bn = 0x7FFFFFFF;
        auto exact1 = [&](int ci) {
            const float* cr = cent + (size_t)ci * D_DIM + lane * 8;
            fx4 cc0 = *(const fx4*)cr, cc1 = *(const fx4*)(cr + 4);
            float dp = z8[0] * cc0.x + z8[1] * cc0.y + z8[2] * cc0.z + z8[3] * cc0.w
                     + z8[4] * cc1.x + z8[5] * cc1.y + z8[6] * cc1.z + z8[7] * cc1.w;
#pragma unroll
            for (int off = 1; off < 64; off <<= 1) dp += __shfl_xor(dp, off);
            float de = cnorm[ci] - 2.0f * dp;
            if (de < bd || (de == bd && ci < bn)) { bd = de; bn = ci; }
        };
        unsigned long long m = b0;
        while (m) { int src = __ffsll(m) - 1; m &= m - 1; exact1(__shfl((int)w4.y, src)); }
        m = b1;
        while (m) { int src = __ffsll(m) - 1; m &= m - 1; exact1(__shfl((int)w4.w, src)); }
        if (ovf) {
#pragma unroll
            for (int q = 0; q < 4; ++q) {
                int cf = (q == 0) ? c0 : (q == 1) ? c1 : (q == 2) ? c2 : c3;
                if (cf > QSLOTS)
                    for (int n0 = 0; n0 < 512; ++n0) exact1(q * 512 + n0);
            }
        }
        ans = bn;
    }
    const float* dr = dec + (size_t)ans * F_OUT;
    float* orow = out + (size_t)token * F_OUT;
    orow[lane] = dr[lane];
    if (lane < F_OUT - 64) orow[64 + lane] = dr[64 + lane];
}

// ============================ fallback path (round-1, known-good) ============================
__global__ void k_transpose(const float* __restrict__ cent, float* __restrict__ centT) {
    __shared__ float tile[64][65];
    int kb = blockIdx.x * 64, db = blockIdx.y * 64;
    int lx = threadIdx.x & 63, ly = threadIdx.x >> 6;
#pragma unroll
    for (int i = 0; i < 16; ++i) {
        int row = ly + i * 4;
        tile[row][lx] = cent[(size_t)(kb + row) * D_DIM + db + lx];
    }
    __syncthreads();
#pragma unroll
    for (int i = 0; i < 16; ++i) {
        int row = ly + i * 4;
        centT[(size_t)(db + row) * K_CENT + kb + lx] = tile[lx][row];
    }
}

__global__ void k_cnorm(const float* __restrict__ cent, float* __restrict__ cnorm) {
    int wave = threadIdx.x >> 6, lane = threadIdx.x & 63;
    int k = blockIdx.x * 4 + wave;
    const float* row = cent + (size_t)k * D_DIM;
    float s = 0.f;
#pragma unroll
    for (int j = 0; j < 8; ++j) { float v = row[lane + 64 * j]; s += v * v; }
#pragma unroll
    for (int off = 32; off; off >>= 1) s += __shfl_down(s, off);
    if (lane == 0) cnorm[k] = s;
}

__global__ void k_dec(const float* __restrict__ cent, const float* __restrict__ Wdec,
                      const float* __restrict__ bdec, float* __restrict__ dec) {
    __shared__ float cs[D_DIM];
    int k = blockIdx.x;
    for (int d = threadIdx.x; d < D_DIM; d += blockDim.x) cs[d] = cent[(size_t)k * D_DIM + d];
    __syncthreads();
    int f = threadIdx.x;
    if (f < F_OUT) {
        float a0 = 0.f, a1 = 0.f, a2 = 0.f, a3 = 0.f;
#pragma unroll 4
        for (int d = 0; d < D_DIM; d += 4) {
            a0 += cs[d + 0] * Wdec[(d + 0) * F_OUT + f];
            a1 += cs[d + 1] * Wdec[(d + 1) * F_OUT + f];
            a2 += cs[d + 2] * Wdec[(d + 2) * F_OUT + f];
            a3 += cs[d + 3] * Wdec[(d + 3) * F_OUT + f];
        }
        dec[(size_t)k * F_OUT + f] = a0 + a1 + a2 + a3 + bdec[f];
    }
}

__global__ void k_out(const float* __restrict__ dec, const int* __restrict__ idx,
                      float* __restrict__ out) {
    int e0 = blockIdx.x * 2560;
#pragma unroll
    for (int r = 0; r < 10; ++r) {
        int e = e0 + threadIdx.x + r * 256;
        int n = e / F_OUT, f = e - n * F_OUT;
        out[e] = dec[(size_t)idx[n] * F_OUT + f];
    }
}

__global__ __launch_bounds__(256) void k_main(
    const float* __restrict__ x, const float* __restrict__ Wenc,
    const float* __restrict__ benc, const float* __restrict__ centT,
    const float* __restrict__ cnorm, int* __restrict__ idxOut) {
    __shared__ float xs[TM * F_IN];
    __shared__ float zs[TM][D_DIM];
    float* pv = &zs[0][0];
    int*   pi = (int*)(&zs[0][0] + 256 * TM);
    const int tid = threadIdx.x;
    const int tok0 = blockIdx.x * TM;
    for (int e = tid; e < TM * F_IN; e += 256) xs[e] = x[(size_t)tok0 * F_IN + e];
    __syncthreads();
    {
        float acc0[TM], acc1[TM];
#pragma unroll
        for (int t = 0; t < TM; ++t) { acc0[t] = 0.f; acc1[t] = 0.f; }
        const float2 b2 = ((const float2*)benc)[tid];
#pragma unroll 4
        for (int f4 = 0; f4 < F_IN; f4 += 4) {
            float2 w0 = ((const float2*)(Wenc + (size_t)(f4 + 0) * D_DIM))[tid];
            float2 w1 = ((const float2*)(Wenc + (size_t)(f4 + 1) * D_DIM))[tid];
            float2 w2 = ((const float2*)(Wenc + (size_t)(f4 + 2) * D_DIM))[tid];
            float2 w3 = ((const float2*)(Wenc + (size_t)(f4 + 3) * D_DIM))[tid];
#pragma unroll
            for (int t = 0; t < TM; ++t) {
                float4 xv = *(const float4*)&xs[t * F_IN + f4];
                acc0[t] += xv.x * w0.x + xv.y * w1.x + xv.z * w2.x + xv.w * w3.x;
                acc1[t] += xv.x * w0.y + xv.y * w1.y + xv.z * w2.y + xv.w * w3.y;
            }
        }
#pragma unroll
        for (int t = 0; t < TM; ++t)
            *(float2*)&zs[t][2 * tid] = make_float2(acc0[t] + b2.x, acc1[t] + b2.y);
    }
    __syncthreads();
    float minv[TM]; int mini[TM];
#pragma unroll
    for (int t = 0; t < TM; ++t) { minv[t] = 3.4e38f; mini[t] = 0; }
    for (int iter = 0; iter < 2; ++iter) {
        float acc[4][TM];
#pragma unroll
        for (int j = 0; j < 4; ++j)
#pragma unroll
            for (int t = 0; t < TM; ++t) acc[j][t] = 0.f;
        const int cbase = iter * 1024 + tid;
        for (int d4 = 0; d4 < D_DIM; d4 += 4) {
            float cv[4][4];
#pragma unroll
            for (int dd = 0; dd < 4; ++dd) {
                const float* cp = centT + (size_t)(d4 + dd) * K_CENT + cbase;
                cv[dd][0] = cp[0]; cv[dd][1] = cp[256]; cv[dd][2] = cp[512]; cv[dd][3] = cp[768];
            }
#pragma unroll
            for (int t = 0; t < TM; ++t) {
                float4 zv = *(const float4*)&zs[t][d4];
#pragma unroll
                for (int j = 0; j < 4; ++j)
                    acc[j][t] += zv.x * cv[0][j] + zv.y * cv[1][j] + zv.z * cv[2][j] + zv.w * cv[3][j];
            }
        }
#pragma unroll
        for (int j = 0; j < 4; ++j) {
            int c = cbase + j * 256;
            float cn = cnorm[c];
#pragma unroll
            for (int t = 0; t < TM; ++t) {
                float dist = cn - 2.f * acc[j][t];
                if (dist < minv[t]) { minv[t] = dist; mini[t] = c; }
            }
        }
    }
    __syncthreads();
#pragma unroll
    for (int t = 0; t < TM; ++t) { pv[tid * TM + t] = minv[t]; pi[tid * TM + t] = mini[t]; }
    __syncthreads();
    {
        int t = tid & 15, g = tid >> 4;
        float bv = 3.4e38f; int bi = 0x7fffffff;
        for (int j = 0; j < 16; ++j) {
            int r2 = g + 16 * j;
            float vv = pv[r2 * TM + t]; int i2 = pi[r2 * TM + t];
            if (vv < bv || (vv == bv && i2 < bi)) { bv = vv; bi = i2; }
        }
        pv[g * TM + t] = bv; pi[g * TM + t] = bi;
    }
    __syncthreads();
    if (tid < TM) {
        int t = tid;
        float bv = 3.4e38f; int bi = 0x7fffffff;
        for (int g = 0; g < 16; ++g) {
            float vv = pv[g * TM + t]; int i2 = pi[g * TM + t];
            if (vv < bv || (vv == bv && i2 < bi)) { bv = vv; bi = i2; }
        }
        idxOut[tok0 + t] = bi;
    }
}

// ============================ launch ============================
extern "C" void kernel_launch(void* const* d_in, const int* in_sizes, int n_in,
                              void* d_out, int out_size, void* d_ws, size_t ws_size,
                              hipStream_t stream) {
    const float* x    = (const float*)d_in[0];
    const float* Wenc = (const float*)d_in[1];
    const float* benc = (const float*)d_in[2];
    const float* cent = (const float*)d_in[3];
    const float* Wdec = (const float*)d_in[4];
    const float* bdec = (const float*)d_in[5];
    float* out = (float*)d_out;

    const size_t L_B  = (size_t)N_TOK * TREC;            // 26214400 candidate lists
    const size_t XB_B = (size_t)N_TOK * KP * 2;          //  6291456 xbt
    const size_t GB_B = (size_t)K_CENT * KP * 2;         //   393216 Gbt
    const size_t N_B  = (size_t)K_CENT * 4;              //     8192 cnorm
    const size_t D_B  = (size_t)K_CENT * F_OUT * 4;      //   655360 dec
    const size_t BC_B = (size_t)D_DIM * JTOT * 4;        //   327680 Bcat
    const size_t NEED = L_B + XB_B + GB_B + N_B + D_B + BC_B;

    if (ws_size >= NEED) {
        char* w = (char*)d_ws;
        char*           lists = w;                            w += L_B;
        unsigned short* xbt   = (unsigned short*)w;           w += XB_B;
        unsigned short* Gbt   = (unsigned short*)w;           w += GB_B;
        float*          cnorm = (float*)w;                    w += N_B;
        float*          dec   = (float*)w;                    w += D_B;
        float*          Bcat  = (float*)w;

        k_prep1<<<2368, 256, 0, stream>>>(x, Wenc, Wdec, cent, benc,
                                          xbt, Bcat, cnorm, Gbt);
        k_cgemm2<<<K_CENT / 4, 384, 0, stream>>>(cent, Bcat, bdec, Gbt, dec);
        k_dist3<<<1024, 512, 0, stream>>>(xbt, Gbt, lists);
        k_merge4<<<N_TOK / 4, 256, 0, stream>>>(lists, cnorm, cent, x, Wenc, benc, dec, out);
    } else {
        float* centT = (float*)d_ws;
        float* cnorm = centT + (size_t)D_DIM * K_CENT;
        float* dec   = cnorm + K_CENT;
        int*   idx   = (int*)(dec + (size_t)K_CENT * F_OUT);
        k_transpose<<<dim3(K_CENT / 64, D_DIM / 64), 256, 0, stream>>>(cent, centT);
        k_cnorm<<<K_CENT / 4, 256, 0, stream>>>(cent, cnorm);
        k_dec<<<K_CENT, 128, 0, stream>>>(cent, Wdec, bdec, dec);
        k_main<<<N_TOK / TM, 256, 0, stream>>>(x, Wenc, benc, centT, cnorm, idx);
        k_out<<<N_TOK * F_OUT / 2560, 256, 0, stream>>>(dec, idx, out);
    }
}